// Round 14
// baseline (164.346 us; speedup 1.0000x reference)
//
#include <hip/hip_runtime.h>
#include <hip/hip_bf16.h>
#include <cstdint>
#include <cmath>

#define BDIM 256

constexpr int Bb = 2;
constexpr int Nn = 2048;
constexpr int Cc = 768;
constexpr int Hh = 12;
constexpr int Dd = 64;
constexpr int TC = 3 * Cc;   // 2304
constexpr int BH = Bb * Hh;  // 24
constexpr int NCHUNK = 16;
constexpr int CHROWS = Nn / NCHUNK;  // 128

typedef __attribute__((ext_vector_type(8))) short short8v;
typedef __attribute__((ext_vector_type(4))) float f32x4;

__device__ __forceinline__ float elu1(float x) {
  return x > 0.f ? x + 1.f : expf(x);
}

__device__ __forceinline__ unsigned short f2bf(float f) {
  uint32_t u = __float_as_uint(f);
  uint32_t r = (u + 0x7fff + ((u >> 16) & 1)) >> 16;
  return (unsigned short)r;
}
__device__ __forceinline__ float bf2f(unsigned short h) {
  return __uint_as_float(((uint32_t)h) << 16);
}

__device__ __forceinline__ void gll16(const unsigned short* g, unsigned short* ldsbase) {
  __builtin_amdgcn_global_load_lds((const __attribute__((address_space(1))) void*)g,
                                   (__attribute__((address_space(3))) void*)ldsbase,
                                   16, 0, 0);
}

// ---------------- fused input casts ---------------------------------------------------
constexpr int XBLK = 3072;
constexpr int WQBLK = (TC / 32) * (Cc / 32);     // 1728
constexpr int WPBLK = (Cc / 32) * (Cc / 32);     // 576

__device__ __forceinline__ void castT_tile(const float* __restrict__ W,
                                           unsigned short* __restrict__ Wh,
                                           int K, int N, int n0, int k0, int tid,
                                           float (*t)[33]) {
  const int r = tid >> 3, c4 = (tid & 7) * 4;
  float4 v = *(const float4*)&W[(size_t)(k0 + r) * N + n0 + c4];
  t[r][c4 + 0] = v.x;
  t[r][c4 + 1] = v.y;
  t[r][c4 + 2] = v.z;
  t[r][c4 + 3] = v.w;
  __syncthreads();
  const int n = tid >> 3, k4 = (tid & 7) * 4;
  ushort4 h;
  h.x = f2bf(t[k4 + 0][n]);
  h.y = f2bf(t[k4 + 1][n]);
  h.z = f2bf(t[k4 + 2][n]);
  h.w = f2bf(t[k4 + 3][n]);
  *(ushort4*)&Wh[(size_t)(n0 + n) * K + k0 + k4] = h;
}

__global__ __launch_bounds__(BDIM) void fused_cast(const float* __restrict__ x,
                                                   const float* __restrict__ w_qkv,
                                                   const float* __restrict__ w_proj,
                                                   unsigned short* __restrict__ xh,
                                                   unsigned short* __restrict__ wqh,
                                                   unsigned short* __restrict__ wph) {
  __shared__ float t[32][33];
  const int bid = blockIdx.x, tid = threadIdx.x;
  if (bid < XBLK) {
    int i = (bid * BDIM + tid) * 4;
    float4 v = *(const float4*)&x[i];
    ushort4 h;
    h.x = f2bf(v.x);
    h.y = f2bf(v.y);
    h.z = f2bf(v.z);
    h.w = f2bf(v.w);
    *(ushort4*)&xh[i] = h;
  } else if (bid < XBLK + WQBLK) {
    int q = bid - XBLK;
    castT_tile(w_qkv, wqh, Cc, TC, (q % (TC / 32)) * 32, (q / (TC / 32)) * 32, tid, t);
  } else {
    int p = bid - XBLK - WQBLK;
    castT_tile(w_proj, wph, Cc, Cc, (p % (Cc / 32)) * 32, (p / (Cc / 32)) * 32, tid, t);
  }
}

// ---------------- 2-phase MFMA core (device-inline) -----------------------------------
// EP=0: plain + bias direct stores (proj).
// EP=1: in-kernel denom from kss + LDS-transposed plain f32x4 stores (attn).
// EP=2: qkv epilogue (elu+1, [B,H,N,D] bf16 scatter).
template <int EP>
__device__ __forceinline__ void mfma_core(
    int bx, int by, int bz,
    const unsigned short* __restrict__ A, const unsigned short* __restrict__ Bt,
    const float* __restrict__ bias,
    float* __restrict__ C, int Mrows, int Nw, int K,
    long sAz, long sBz, long sCz,
    unsigned short* __restrict__ qpb, unsigned short* __restrict__ kpb,
    unsigned short* __restrict__ vpb,
    unsigned short* lds, const float* kss, float* dnls) {
  const unsigned short* A0 = A + (size_t)bz * sAz;
  const unsigned short* B0 = Bt + (size_t)bz * sBz;
  float* Cz = C + (size_t)bz * sCz;

  const int tid = threadIdx.x;
  const int wave = tid >> 6, lane = tid & 63;
  const int wr = wave >> 1, wc = wave & 1;
  const int row0 = by * 128, col0 = bx * 128;
  const int l15 = lane & 15, l4 = lane >> 4;
  const int srow = wave * 16 + (lane >> 2);
  const int scol = (lane & 3) * 8;
  const int wbase = wave * 512;

  auto STAGE = [&](int buf, int k0) {
    unsigned short* dst = lds + buf * 8192 + wbase;
    gll16(&A0[(size_t)(row0 + srow) * K + k0 + scol], dst);
    gll16(&A0[(size_t)(row0 + 64 + srow) * K + k0 + scol], dst + 2048);
    gll16(&B0[(size_t)(col0 + srow) * K + k0 + scol], dst + 4096);
    gll16(&B0[(size_t)(col0 + 64 + srow) * K + k0 + scol], dst + 6144);
  };

  f32x4 acc[4][4];
#pragma unroll
  for (int i = 0; i < 4; ++i)
#pragma unroll
    for (int j = 0; j < 4; ++j) acc[i][j] = {0.f, 0.f, 0.f, 0.f};

  auto COMPUTE = [&](int buf) {
    const unsigned short* la = lds + buf * 8192;
    const unsigned short* lb = la + 4096;
    short8v av[4], bv[4];
#pragma unroll
    for (int i = 0; i < 4; ++i)
      av[i] = *(const short8v*)&la[(wr * 64 + i * 16 + l15) * 32 + l4 * 8];
#pragma unroll
    for (int j = 0; j < 4; ++j)
      bv[j] = *(const short8v*)&lb[(wc * 64 + j * 16 + l15) * 32 + l4 * 8];
#pragma unroll
    for (int i = 0; i < 4; ++i)
#pragma unroll
      for (int j = 0; j < 4; ++j)
        acc[i][j] = __builtin_amdgcn_mfma_f32_16x16x32_bf16(av[i], bv[j], acc[i][j], 0, 0, 0);
  };

  const int nt = K >> 5;
  STAGE(0, 0);
  if (nt > 1) STAGE(1, 32);
  int cur = 0;
  for (int t = 0; t < nt; ++t) {
    if (t < nt - 1)
      asm volatile("s_waitcnt vmcnt(4)" ::: "memory");
    else
      asm volatile("s_waitcnt vmcnt(0)" ::: "memory");
    __builtin_amdgcn_s_barrier();
    COMPUTE(cur);
    if (t < nt - 2) {
      __builtin_amdgcn_s_barrier();
      STAGE(cur, (t + 2) * 32);
    }
    cur ^= 1;
  }

  if constexpr (EP == 0) {
    // proj: direct stores + bias (plain)
#pragma unroll
    for (int i = 0; i < 4; ++i) {
      const int rbase = row0 + wr * 64 + i * 16 + l4 * 4;
#pragma unroll
      for (int j = 0; j < 4; ++j) {
        const int col = col0 + wc * 64 + j * 16 + l15;
        float bs = bias[col];
#pragma unroll
        for (int r = 0; r < 4; ++r)
          Cz[(size_t)(rbase + r) * Nw + col] = acc[i][j][r] + bs;
      }
    }
  } else if constexpr (EP == 1) {
    // in-kernel denom: A-frags (still resident in bufs 0/1 for K=64) . kss
    float dp[4] = {0.f, 0.f, 0.f, 0.f};
#pragma unroll
    for (int ks = 0; ks < 2; ++ks)
#pragma unroll
      for (int i = 0; i < 4; ++i) {
        short8v a8 = *(const short8v*)&lds[ks * 8192 + (wr * 64 + i * 16 + l15) * 32 + l4 * 8];
#pragma unroll
        for (int t = 0; t < 8; ++t)
          dp[i] += bf2f((unsigned short)a8[t]) * kss[ks * 32 + l4 * 8 + t];
      }
#pragma unroll
    for (int i = 0; i < 4; ++i) {
      dp[i] += __shfl_xor(dp[i], 16);
      dp[i] += __shfl_xor(dp[i], 32);
      if (wc == 0 && l4 == 0) dnls[wr * 64 + i * 16 + l15] = 1.0f / dp[i];
    }
    float* fl = (float*)lds;  // 32 rows x 132 floats
#pragma unroll
    for (int i = 0; i < 4; ++i) {
      __syncthreads();
#pragma unroll
      for (int j = 0; j < 4; ++j)
#pragma unroll
        for (int r = 0; r < 4; ++r)
          fl[(wr * 16 + l4 * 4 + r) * 132 + wc * 64 + j * 16 + l15] =
              acc[i][j][r] * dnls[wr * 64 + i * 16 + l4 * 4 + r];
      __syncthreads();
#pragma unroll
      for (int p = 0; p < 4; ++p) {
        int f4 = p * 256 + tid;
        int cr = f4 >> 5, c4 = (f4 & 31) * 4;
        f32x4 v = *(const f32x4*)&fl[cr * 132 + c4];
        int grow = row0 + (cr >> 4) * 64 + i * 16 + (cr & 15);
        *(f32x4*)&Cz[(size_t)grow * Nw + col0 + c4] = v;  // plain store
      }
    }
  } else {
    // qkv epilogue: elu+1 (q,k) and [B,H,N,D] bf16 scatter (R12-proven form)
    const int tt = bx / 6;  // 0=q, 1=k, 2=v
    const int rcbase = (bx % 6) * 128 + wc * 64;
#pragma unroll
    for (int i = 0; i < 4; ++i) {
      const int rowb = row0 + wr * 64 + i * 16 + l4 * 4;
#pragma unroll
      for (int j = 0; j < 4; ++j) {
        const int rc = rcbase + j * 16 + l15;
        const int h = rc >> 6, d = rc & 63;
#pragma unroll
        for (int r = 0; r < 4; ++r) {
          const int row = rowb + r;
          const int b = row >> 11, n = row & (Nn - 1);
          const size_t idx = ((size_t)(b * Hh + h) * Nn + n) * 64 + d;
          float val = acc[i][j][r];
          if (tt == 0) {
            qpb[idx] = f2bf(elu1(val));
          } else if (tt == 1) {
            kpb[idx] = f2bf(elu1(val));
          } else {
            vpb[idx] = f2bf(val);
          }
        }
      }
    }
  }
}

// ---------------- gemm_qkv: XCD-swizzled 1D grid (576 blocks) -------------------------
__global__ __launch_bounds__(BDIM) void gemm_qkv_k(
    const unsigned short* __restrict__ xh, const unsigned short* __restrict__ wqh,
    unsigned short* __restrict__ qpb, unsigned short* __restrict__ kpb,
    unsigned short* __restrict__ vpb) {
  __shared__ __align__(16) unsigned short lds[16384];
  const int bid = blockIdx.x;                 // 576 = 72 per XCD
  const int swz = (bid & 7) * 72 + (bid >> 3);
  const int bx = swz % 18, by = swz / 18;
  mfma_core<2>(bx, by, 0, xh, wqh, nullptr, nullptr, Bb * Nn, TC, Cc,
               0, 0, 0, qpb, kpb, vpb, lds, nullptr, nullptr);
}

// ---------------- union kernel: attn (6144 blocks, swizzled) + proj (192) -------------
__global__ __launch_bounds__(BDIM) void attn_proj_k(
    const unsigned short* __restrict__ qpb, const unsigned short* __restrict__ kpb,
    const float* __restrict__ ksum, float* __restrict__ attn,
    const unsigned short* __restrict__ oph, const unsigned short* __restrict__ wph,
    const float* __restrict__ b_proj, float* __restrict__ out) {
  __shared__ __align__(16) unsigned short lds[16384];
  __shared__ float kss[64];
  __shared__ float dnls[128];
  const int bid = blockIdx.x, tid = threadIdx.x;
  if (bid < 6144) {
    // XCD swizzle: each XCD owns 768 consecutive = 3 whole bh (256 blocks/bh)
    const int swz = (bid & 7) * 768 + (bid >> 3);
    const int bz = swz >> 8, rem = swz & 255;
    const int by = rem >> 4, bx = rem & 15;
    if (tid < 64) kss[tid] = ksum[bz * 64 + tid];
    asm volatile("s_waitcnt lgkmcnt(0)" ::: "memory");  // kss visible before barriers
    mfma_core<1>(bx, by, bz, qpb, kpb, nullptr, attn, Nn, Nn, Dd,
                 (long)Nn * Dd, (long)Nn * Dd, (long)Nn * Nn,
                 nullptr, nullptr, nullptr, lds, kss, dnls);
  } else {
    const int p = bid - 6144;
    mfma_core<0>(p % 6, p / 6, 0, oph, wph, b_proj, out, Bb * Nn, Cc, Cc,
                 0, 0, 0, nullptr, nullptr, nullptr, lds, nullptr, nullptr);
  }
}

// -------- partial KV = k'^T v (bf16 in, fp32 acc) and Ksum = sum_n k' ----------------
__global__ __launch_bounds__(BDIM) void kv_partial(const unsigned short* __restrict__ kpb,
                                                   const unsigned short* __restrict__ vpb,
                                                   float* __restrict__ kvpart,
                                                   float* __restrict__ kspart) {
  const int chunk = blockIdx.x, bh = blockIdx.y;
  __shared__ unsigned short ks[16][64];
  __shared__ unsigned short vs[16][64];
  __shared__ float ksl[16][64];
  const int tid = threadIdx.x;
  const int e = tid & 63, dg = tid >> 6;
  const int srow = tid >> 4, sd4 = (tid & 15) * 4;
  float acc[16] = {};
  float ksp[4] = {0.f, 0.f, 0.f, 0.f};
  const int n0base = chunk * CHROWS;
  for (int s = 0; s < CHROWS; s += 16) {
    const int n = n0base + s + srow;
    ushort4 kk = *(const ushort4*)&kpb[((size_t)bh * Nn + n) * 64 + sd4];
    ushort4 vv = *(const ushort4*)&vpb[((size_t)bh * Nn + n) * 64 + sd4];
    __syncthreads();
    *(ushort4*)&ks[srow][sd4] = kk;
    *(ushort4*)&vs[srow][sd4] = vv;
    ksp[0] += bf2f(kk.x);
    ksp[1] += bf2f(kk.y);
    ksp[2] += bf2f(kk.z);
    ksp[3] += bf2f(kk.w);
    __syncthreads();
#pragma unroll
    for (int j = 0; j < 16; ++j) {
      const float v = bf2f(vs[j][e]);
      short8v k8a = *(const short8v*)&ks[j][dg * 16];
      short8v k8b = *(const short8v*)&ks[j][dg * 16 + 8];
#pragma unroll
      for (int d = 0; d < 8; ++d) acc[d] += bf2f((unsigned short)k8a[d]) * v;
#pragma unroll
      for (int d = 0; d < 8; ++d) acc[8 + d] += bf2f((unsigned short)k8b[d]) * v;
    }
  }
  float* outp = kvpart + (size_t)(bh * NCHUNK + chunk) * 4096;
#pragma unroll
  for (int d = 0; d < 16; ++d) outp[(dg * 16 + d) * 64 + e] = acc[d];
  ksl[srow][sd4 + 0] = ksp[0];
  ksl[srow][sd4 + 1] = ksp[1];
  ksl[srow][sd4 + 2] = ksp[2];
  ksl[srow][sd4 + 3] = ksp[3];
  __syncthreads();
  if (tid < 64) {
    float s2 = 0.f;
#pragma unroll
    for (int r = 0; r < 16; ++r) s2 += ksl[r][tid];
    kspart[(bh * NCHUNK + chunk) * 64 + tid] = s2;
  }
}

// -------- reduce: KV^T -> bf16 [dv][dk], ksum fp32; grid (16, BH) --------------------
__global__ __launch_bounds__(BDIM) void kv_reduce(const float* __restrict__ kvpart,
                                                  const float* __restrict__ kspart,
                                                  unsigned short* __restrict__ kvtb,
                                                  float* __restrict__ ksum) {
  const int seg = blockIdx.x, bh = blockIdx.y, tid = threadIdx.x;
  const int idx = seg * 256 + tid;
  float s = 0.f;
#pragma unroll 4
  for (int c = 0; c < NCHUNK; ++c) s += kvpart[(size_t)(bh * NCHUNK + c) * 4096 + idx];
  const int dk = idx >> 6, dv = idx & 63;
  kvtb[(size_t)bh * 4096 + dv * 64 + dk] = f2bf(s);
  if (tid < 4) {
    int e = seg * 4 + tid;
    float s2 = 0.f;
#pragma unroll 4
    for (int c = 0; c < NCHUNK; ++c) s2 += kspart[(bh * NCHUNK + c) * 64 + e];
    ksum[bh * 64 + e] = s2;
  }
}

// ------ fused MFMA outpre: oph = (q'.KV)/denom (denom in-kernel, not stored) ---------
__global__ __launch_bounds__(BDIM) void outpre_mfma(
    const unsigned short* __restrict__ qpb, const unsigned short* __restrict__ kvtb,
    const float* __restrict__ ksum, unsigned short* __restrict__ oph) {
  const int nc = blockIdx.x, bh = blockIdx.y;
  const int b = bh / Hh, h = bh % Hh;
  __shared__ float kss[64];
  __shared__ float dnls[128];
  const int tid = threadIdx.x;
  const int wv = tid >> 6, lane = tid & 63;
  const int l15 = lane & 15, l4 = lane >> 4;
  if (tid < 64) kss[tid] = ksum[bh * 64 + tid];

  const int rowb = nc * 128 + wv * 32;
  const unsigned short* Aq = qpb + ((size_t)bh * Nn + rowb) * 64;
  const unsigned short* Bk = kvtb + (size_t)bh * 4096;

  short8v av[2][2], bv[4][2];
#pragma unroll
  for (int ks = 0; ks < 2; ++ks) {
#pragma unroll
    for (int i = 0; i < 2; ++i)
      av[i][ks] = *(const short8v*)&Aq[(size_t)(i * 16 + l15) * 64 + ks * 32 + l4 * 8];
#pragma unroll
    for (int j = 0; j < 4; ++j)
      bv[j][ks] = *(const short8v*)&Bk[(size_t)(j * 16 + l15) * 64 + ks * 32 + l4 * 8];
  }
  f32x4 acc[2][4];
#pragma unroll
  for (int i = 0; i < 2; ++i)
#pragma unroll
    for (int j = 0; j < 4; ++j) acc[i][j] = {0.f, 0.f, 0.f, 0.f};
#pragma unroll
  for (int ks = 0; ks < 2; ++ks)
#pragma unroll
    for (int i = 0; i < 2; ++i)
#pragma unroll
      for (int j = 0; j < 4; ++j)
        acc[i][j] = __builtin_amdgcn_mfma_f32_16x16x32_bf16(av[i][ks], bv[j][ks],
                                                            acc[i][j], 0, 0, 0);

  __syncthreads();
  float dpart[2] = {0.f, 0.f};
#pragma unroll
  for (int ks = 0; ks < 2; ++ks)
#pragma unroll
    for (int i = 0; i < 2; ++i)
#pragma unroll
      for (int t = 0; t < 8; ++t)
        dpart[i] += bf2f((unsigned short)av[i][ks][t]) * kss[ks * 32 + l4 * 8 + t];
#pragma unroll
  for (int i = 0; i < 2; ++i) {
    dpart[i] += __shfl_xor(dpart[i], 16);
    dpart[i] += __shfl_xor(dpart[i], 32);
    if (l4 == 0) dnls[wv * 32 + i * 16 + l15] = dpart[i];
  }
  __syncthreads();
#pragma unroll
  for (int i = 0; i < 2; ++i) {
#pragma unroll
    for (int r = 0; r < 4; ++r) {
      const int rl = i * 16 + l4 * 4 + r;
      const float rd = 1.0f / dnls[wv * 32 + rl];
      const int nrow = rowb + rl;
#pragma unroll
      for (int j = 0; j < 4; ++j)
        oph[((size_t)b * Nn + nrow) * Cc + h * 64 + j * 16 + l15] =
            f2bf(acc[i][j][r] * rd);
    }
  }
}

extern "C" void kernel_launch(void* const* d_in, const int* in_sizes, int n_in,
                              void* d_out, int out_size, void* d_ws, size_t ws_size,
                              hipStream_t stream) {
  const float* x = (const float*)d_in[0];
  const float* w_qkv = (const float*)d_in[1];
  const float* w_proj = (const float*)d_in[2];
  const float* b_proj = (const float*)d_in[3];
  float* out = (float*)d_out;
  float* attn = out + (size_t)Bb * Nn * Cc;

  float* ws = (float*)d_ws;
  float* kvpart = ws;                        // 1572864
  float* kspart = kvpart + 1572864;          // 24576
  float* ksum = kspart + 24576;              // 2048 (padded)
  float* denom_unused = ksum + 2048;         // 49152 (layout stability)
  unsigned short* us = (unsigned short*)(denom_unused + 49152);
  unsigned short* xh = us;                   // 3145728
  unsigned short* wqh = xh + 3145728;        // 1769472
  unsigned short* qpb = wqh + 1769472;       // 3145728
  unsigned short* kpb = qpb + 3145728;       // 3145728
  unsigned short* vpb = kpb + 3145728;       // 3145728
  unsigned short* kvtb = vpb + 3145728;      // 98304
  unsigned short* oph = kvtb + 98304;        // 3145728
  unsigned short* wph = oph + 3145728;       // 589824

  // 1. input casts
  fused_cast<<<dim3(XBLK + WQBLK + WPBLK), BDIM, 0, stream>>>(x, w_qkv, w_proj, xh, wqh,
                                                              wph);
  // 2. qkv GEMM (XCD-swizzled), fused elu+1 + [B,H,N,D] bf16 epilogue
  gemm_qkv_k<<<dim3(576), BDIM, 0, stream>>>(xh, wqh, qpb, kpb, vpb);
  // 3-4. KV = k'^T v, reduce -> KV^T bf16 + ksum
  kv_partial<<<dim3(NCHUNK, BH), BDIM, 0, stream>>>(kpb, vpb, kvpart, kspart);
  kv_reduce<<<dim3(16, BH), BDIM, 0, stream>>>(kvpart, kspart, kvtb, ksum);
  // 5. out_pre via register MFMA (denom in-kernel)
  outpre_mfma<<<dim3(Nn / 128, BH), BDIM, 0, stream>>>(qpb, kvtb, ksum, oph);
  // 6. attn (in-kernel denom, swizzled, plain stores) UNION proj
  attn_proj_k<<<dim3(6144 + 192), BDIM, 0, stream>>>(qpb, kpb, ksum, attn,
                                                     oph, wph, b_proj, out);
}

// Round 15
// 149.631 us; speedup vs baseline: 1.0983x; 1.0983x over previous
//
#include <hip/hip_runtime.h>
#include <hip/hip_bf16.h>
#include <cstdint>
#include <cmath>

#define BDIM 256

constexpr int Bb = 2;
constexpr int Nn = 2048;
constexpr int Cc = 768;
constexpr int Hh = 12;
constexpr int Dd = 64;
constexpr int TC = 3 * Cc;   // 2304
constexpr int BH = Bb * Hh;  // 24
constexpr int NCHUNK = 16;
constexpr int CHROWS = Nn / NCHUNK;  // 128

typedef __attribute__((ext_vector_type(8))) short short8v;
typedef __attribute__((ext_vector_type(4))) float f32x4;

__device__ __forceinline__ float elu1(float x) {
  return x > 0.f ? x + 1.f : expf(x);
}

__device__ __forceinline__ unsigned short f2bf(float f) {
  uint32_t u = __float_as_uint(f);
  uint32_t r = (u + 0x7fff + ((u >> 16) & 1)) >> 16;
  return (unsigned short)r;
}
__device__ __forceinline__ float bf2f(unsigned short h) {
  return __uint_as_float(((uint32_t)h) << 16);
}

__device__ __forceinline__ void gll16(const unsigned short* g, unsigned short* ldsbase) {
  __builtin_amdgcn_global_load_lds((const __attribute__((address_space(1))) void*)g,
                                   (__attribute__((address_space(3))) void*)ldsbase,
                                   16, 0, 0);
}

// ---------------- fused input casts ---------------------------------------------------
constexpr int XBLK = 3072;
constexpr int WQBLK = (TC / 32) * (Cc / 32);     // 1728
constexpr int WPBLK = (Cc / 32) * (Cc / 32);     // 576

__device__ __forceinline__ void castT_tile(const float* __restrict__ W,
                                           unsigned short* __restrict__ Wh,
                                           int K, int N, int n0, int k0, int tid,
                                           float (*t)[33]) {
  const int r = tid >> 3, c4 = (tid & 7) * 4;
  float4 v = *(const float4*)&W[(size_t)(k0 + r) * N + n0 + c4];
  t[r][c4 + 0] = v.x;
  t[r][c4 + 1] = v.y;
  t[r][c4 + 2] = v.z;
  t[r][c4 + 3] = v.w;
  __syncthreads();
  const int n = tid >> 3, k4 = (tid & 7) * 4;
  ushort4 h;
  h.x = f2bf(t[k4 + 0][n]);
  h.y = f2bf(t[k4 + 1][n]);
  h.z = f2bf(t[k4 + 2][n]);
  h.w = f2bf(t[k4 + 3][n]);
  *(ushort4*)&Wh[(size_t)(n0 + n) * K + k0 + k4] = h;
}

__global__ __launch_bounds__(BDIM) void fused_cast(const float* __restrict__ x,
                                                   const float* __restrict__ w_qkv,
                                                   const float* __restrict__ w_proj,
                                                   unsigned short* __restrict__ xh,
                                                   unsigned short* __restrict__ wqh,
                                                   unsigned short* __restrict__ wph) {
  __shared__ float t[32][33];
  const int bid = blockIdx.x, tid = threadIdx.x;
  if (bid < XBLK) {
    int i = (bid * BDIM + tid) * 4;
    float4 v = *(const float4*)&x[i];
    ushort4 h;
    h.x = f2bf(v.x);
    h.y = f2bf(v.y);
    h.z = f2bf(v.z);
    h.w = f2bf(v.w);
    *(ushort4*)&xh[i] = h;
  } else if (bid < XBLK + WQBLK) {
    int q = bid - XBLK;
    castT_tile(w_qkv, wqh, Cc, TC, (q % (TC / 32)) * 32, (q / (TC / 32)) * 32, tid, t);
  } else {
    int p = bid - XBLK - WQBLK;
    castT_tile(w_proj, wph, Cc, Cc, (p % (Cc / 32)) * 32, (p / (Cc / 32)) * 32, tid, t);
  }
}

// ---------------- 2-phase MFMA core (device-inline) -----------------------------------
// EP=0: plain + bias, nt stores (proj).  EP=1: /denom + LDS-transposed nt f32x4 (attn).
// EP=2: qkv epilogue (elu+1, [B,H,N,D] bf16 scatter).
template <int EP>
__device__ __forceinline__ void mfma_core(
    int bx, int by, int bz,
    const unsigned short* __restrict__ A, const unsigned short* __restrict__ Bt,
    const float* __restrict__ bias, const float* __restrict__ denom,
    float* __restrict__ C, int Mrows, int Nw, int K,
    long sAz, long sBz, long sCz,
    unsigned short* __restrict__ qpb, unsigned short* __restrict__ kpb,
    unsigned short* __restrict__ vpb,
    unsigned short* lds, float* dnls) {
  const unsigned short* A0 = A + (size_t)bz * sAz;
  const unsigned short* B0 = Bt + (size_t)bz * sBz;
  float* Cz = C + (size_t)bz * sCz;

  const int tid = threadIdx.x;
  const int wave = tid >> 6, lane = tid & 63;
  const int wr = wave >> 1, wc = wave & 1;
  const int row0 = by * 128, col0 = bx * 128;
  const int l15 = lane & 15, l4 = lane >> 4;
  const int srow = wave * 16 + (lane >> 2);
  const int scol = (lane & 3) * 8;
  const int wbase = wave * 512;

  float dnv_reg = 0.f;
  if constexpr (EP == 1) dnv_reg = denom[(size_t)bz * Mrows + row0 + (tid & 127)];

  auto STAGE = [&](int buf, int k0) {
    unsigned short* dst = lds + buf * 8192 + wbase;
    gll16(&A0[(size_t)(row0 + srow) * K + k0 + scol], dst);
    gll16(&A0[(size_t)(row0 + 64 + srow) * K + k0 + scol], dst + 2048);
    gll16(&B0[(size_t)(col0 + srow) * K + k0 + scol], dst + 4096);
    gll16(&B0[(size_t)(col0 + 64 + srow) * K + k0 + scol], dst + 6144);
  };

  f32x4 acc[4][4];
#pragma unroll
  for (int i = 0; i < 4; ++i)
#pragma unroll
    for (int j = 0; j < 4; ++j) acc[i][j] = {0.f, 0.f, 0.f, 0.f};

  auto COMPUTE = [&](int buf) {
    const unsigned short* la = lds + buf * 8192;
    const unsigned short* lb = la + 4096;
    short8v av[4], bv[4];
#pragma unroll
    for (int i = 0; i < 4; ++i)
      av[i] = *(const short8v*)&la[(wr * 64 + i * 16 + l15) * 32 + l4 * 8];
#pragma unroll
    for (int j = 0; j < 4; ++j)
      bv[j] = *(const short8v*)&lb[(wc * 64 + j * 16 + l15) * 32 + l4 * 8];
#pragma unroll
    for (int i = 0; i < 4; ++i)
#pragma unroll
      for (int j = 0; j < 4; ++j)
        acc[i][j] = __builtin_amdgcn_mfma_f32_16x16x32_bf16(av[i], bv[j], acc[i][j], 0, 0, 0);
  };

  const int nt = K >> 5;
  STAGE(0, 0);
  if (nt > 1) STAGE(1, 32);
  int cur = 0;
  for (int t = 0; t < nt; ++t) {
    if (t < nt - 1)
      asm volatile("s_waitcnt vmcnt(4)" ::: "memory");
    else
      asm volatile("s_waitcnt vmcnt(0)" ::: "memory");
    __builtin_amdgcn_s_barrier();
    COMPUTE(cur);
    if (t < nt - 2) {
      __builtin_amdgcn_s_barrier();
      STAGE(cur, (t + 2) * 32);
    }
    cur ^= 1;
  }

  if constexpr (EP == 0) {
#pragma unroll
    for (int i = 0; i < 4; ++i) {
      const int rbase = row0 + wr * 64 + i * 16 + l4 * 4;
#pragma unroll
      for (int j = 0; j < 4; ++j) {
        const int col = col0 + wc * 64 + j * 16 + l15;
        float bs = bias[col];
#pragma unroll
        for (int r = 0; r < 4; ++r)
          __builtin_nontemporal_store(acc[i][j][r] + bs,
                                      &Cz[(size_t)(rbase + r) * Nw + col]);
      }
    }
  } else if constexpr (EP == 1) {
    if (tid < 128) dnls[tid] = 1.0f / dnv_reg;
    float* fl = (float*)lds;  // 32 rows x 132 floats (padded)
#pragma unroll
    for (int i = 0; i < 4; ++i) {
      __syncthreads();
#pragma unroll
      for (int j = 0; j < 4; ++j)
#pragma unroll
        for (int r = 0; r < 4; ++r)
          fl[(wr * 16 + l4 * 4 + r) * 132 + wc * 64 + j * 16 + l15] =
              acc[i][j][r] * dnls[wr * 64 + i * 16 + l4 * 4 + r];
      __syncthreads();
#pragma unroll
      for (int p = 0; p < 4; ++p) {
        int f4 = p * 256 + tid;
        int cr = f4 >> 5, c4 = (f4 & 31) * 4;
        f32x4 v = *(const f32x4*)&fl[cr * 132 + c4];
        int grow = row0 + (cr >> 4) * 64 + i * 16 + (cr & 15);
        __builtin_nontemporal_store(v, (f32x4*)&Cz[(size_t)grow * Nw + col0 + c4]);
      }
    }
  } else {
    const int tt = bx / 6;  // 0=q, 1=k, 2=v
    const int rcbase = (bx % 6) * 128 + wc * 64;
#pragma unroll
    for (int i = 0; i < 4; ++i) {
      const int rowb = row0 + wr * 64 + i * 16 + l4 * 4;
#pragma unroll
      for (int j = 0; j < 4; ++j) {
        const int rc = rcbase + j * 16 + l15;
        const int h = rc >> 6, d = rc & 63;
#pragma unroll
        for (int r = 0; r < 4; ++r) {
          const int row = rowb + r;
          const int b = row >> 11, n = row & (Nn - 1);
          const size_t idx = ((size_t)(b * Hh + h) * Nn + n) * 64 + d;
          float val = acc[i][j][r];
          if (tt == 0) {
            qpb[idx] = f2bf(elu1(val));
          } else if (tt == 1) {
            kpb[idx] = f2bf(elu1(val));
          } else {
            vpb[idx] = f2bf(val);
          }
        }
      }
    }
  }
}

// ---------------- gemm_qkv: XCD-swizzled 1D grid (576 blocks) -------------------------
__global__ __launch_bounds__(BDIM) void gemm_qkv_k(
    const unsigned short* __restrict__ xh, const unsigned short* __restrict__ wqh,
    unsigned short* __restrict__ qpb, unsigned short* __restrict__ kpb,
    unsigned short* __restrict__ vpb) {
  __shared__ __align__(16) unsigned short lds[16384];
  __shared__ float dnls[128];
  const int bid = blockIdx.x;                 // 576 = 72 per XCD
  const int swz = (bid & 7) * 72 + (bid >> 3);
  const int bx = swz % 18, by = swz / 18;
  mfma_core<2>(bx, by, 0, xh, wqh, nullptr, nullptr, nullptr, Bb * Nn, TC, Cc,
               0, 0, 0, qpb, kpb, vpb, lds, dnls);
}

// ---------------- union kernel: attn (6144 blocks, swizzled) + proj (192) -------------
__global__ __launch_bounds__(BDIM) void attn_proj_k(
    const unsigned short* __restrict__ qpb, const unsigned short* __restrict__ kpb,
    const float* __restrict__ denom, float* __restrict__ attn,
    const unsigned short* __restrict__ oph, const unsigned short* __restrict__ wph,
    const float* __restrict__ b_proj, float* __restrict__ out) {
  __shared__ __align__(16) unsigned short lds[16384];
  __shared__ float dnls[128];
  const int bid = blockIdx.x;
  if (bid < 6144) {
    // XCD swizzle: each XCD owns 768 consecutive = 3 whole bh (256 blocks/bh)
    const int swz = (bid & 7) * 768 + (bid >> 3);
    const int bz = swz >> 8, rem = swz & 255;
    const int by = rem >> 4, bx = rem & 15;
    mfma_core<1>(bx, by, bz, qpb, kpb, nullptr, denom, attn, Nn, Nn, Dd,
                 (long)Nn * Dd, (long)Nn * Dd, (long)Nn * Nn,
                 nullptr, nullptr, nullptr, lds, dnls);
  } else {
    const int p = bid - 6144;
    mfma_core<0>(p % 6, p / 6, 0, oph, wph, b_proj, nullptr, out, Bb * Nn, Cc, Cc,
                 0, 0, 0, nullptr, nullptr, nullptr, lds, dnls);
  }
}

// -------- partial KV = k'^T v (bf16 in, fp32 acc) and Ksum = sum_n k' ----------------
__global__ __launch_bounds__(BDIM) void kv_partial(const unsigned short* __restrict__ kpb,
                                                   const unsigned short* __restrict__ vpb,
                                                   float* __restrict__ kvpart,
                                                   float* __restrict__ kspart) {
  const int chunk = blockIdx.x, bh = blockIdx.y;
  __shared__ unsigned short ks[16][64];
  __shared__ unsigned short vs[16][64];
  __shared__ float ksl[16][64];
  const int tid = threadIdx.x;
  const int e = tid & 63, dg = tid >> 6;
  const int srow = tid >> 4, sd4 = (tid & 15) * 4;
  float acc[16] = {};
  float ksp[4] = {0.f, 0.f, 0.f, 0.f};
  const int n0base = chunk * CHROWS;
  for (int s = 0; s < CHROWS; s += 16) {
    const int n = n0base + s + srow;
    ushort4 kk = *(const ushort4*)&kpb[((size_t)bh * Nn + n) * 64 + sd4];
    ushort4 vv = *(const ushort4*)&vpb[((size_t)bh * Nn + n) * 64 + sd4];
    __syncthreads();
    *(ushort4*)&ks[srow][sd4] = kk;
    *(ushort4*)&vs[srow][sd4] = vv;
    ksp[0] += bf2f(kk.x);
    ksp[1] += bf2f(kk.y);
    ksp[2] += bf2f(kk.z);
    ksp[3] += bf2f(kk.w);
    __syncthreads();
#pragma unroll
    for (int j = 0; j < 16; ++j) {
      const float v = bf2f(vs[j][e]);
      short8v k8a = *(const short8v*)&ks[j][dg * 16];
      short8v k8b = *(const short8v*)&ks[j][dg * 16 + 8];
#pragma unroll
      for (int d = 0; d < 8; ++d) acc[d] += bf2f((unsigned short)k8a[d]) * v;
#pragma unroll
      for (int d = 0; d < 8; ++d) acc[8 + d] += bf2f((unsigned short)k8b[d]) * v;
    }
  }
  float* outp = kvpart + (size_t)(bh * NCHUNK + chunk) * 4096;
#pragma unroll
  for (int d = 0; d < 16; ++d) outp[(dg * 16 + d) * 64 + e] = acc[d];
  ksl[srow][sd4 + 0] = ksp[0];
  ksl[srow][sd4 + 1] = ksp[1];
  ksl[srow][sd4 + 2] = ksp[2];
  ksl[srow][sd4 + 3] = ksp[3];
  __syncthreads();
  if (tid < 64) {
    float s2 = 0.f;
#pragma unroll
    for (int r = 0; r < 16; ++r) s2 += ksl[r][tid];
    kspart[(bh * NCHUNK + chunk) * 64 + tid] = s2;
  }
}

// -------- reduce: KV^T -> bf16 [dv][dk], ksum fp32; grid (16, BH) --------------------
__global__ __launch_bounds__(BDIM) void kv_reduce(const float* __restrict__ kvpart,
                                                  const float* __restrict__ kspart,
                                                  unsigned short* __restrict__ kvtb,
                                                  float* __restrict__ ksum) {
  const int seg = blockIdx.x, bh = blockIdx.y, tid = threadIdx.x;
  const int idx = seg * 256 + tid;
  float s = 0.f;
#pragma unroll 4
  for (int c = 0; c < NCHUNK; ++c) s += kvpart[(size_t)(bh * NCHUNK + c) * 4096 + idx];
  const int dk = idx >> 6, dv = idx & 63;
  kvtb[(size_t)bh * 4096 + dv * 64 + dk] = f2bf(s);
  if (tid < 4) {
    int e = seg * 4 + tid;
    float s2 = 0.f;
#pragma unroll 4
    for (int c = 0; c < NCHUNK; ++c) s2 += kspart[(bh * NCHUNK + c) * 64 + e];
    ksum[bh * 64 + e] = s2;
  }
}

// ------ fused MFMA outpre: denom = q'.ksum (from A-frags); oph = (q'.KV)/denom -------
__global__ __launch_bounds__(BDIM) void outpre_mfma(
    const unsigned short* __restrict__ qpb, const unsigned short* __restrict__ kvtb,
    const float* __restrict__ ksum, float* __restrict__ denom,
    unsigned short* __restrict__ oph) {
  const int nc = blockIdx.x, bh = blockIdx.y;
  const int b = bh / Hh, h = bh % Hh;
  __shared__ float kss[64];
  __shared__ float dnls[128];
  const int tid = threadIdx.x;
  const int wv = tid >> 6, lane = tid & 63;
  const int l15 = lane & 15, l4 = lane >> 4;
  if (tid < 64) kss[tid] = ksum[bh * 64 + tid];

  const int rowb = nc * 128 + wv * 32;
  const unsigned short* Aq = qpb + ((size_t)bh * Nn + rowb) * 64;
  const unsigned short* Bk = kvtb + (size_t)bh * 4096;

  short8v av[2][2], bv[4][2];
#pragma unroll
  for (int ks = 0; ks < 2; ++ks) {
#pragma unroll
    for (int i = 0; i < 2; ++i)
      av[i][ks] = *(const short8v*)&Aq[(size_t)(i * 16 + l15) * 64 + ks * 32 + l4 * 8];
#pragma unroll
    for (int j = 0; j < 4; ++j)
      bv[j][ks] = *(const short8v*)&Bk[(size_t)(j * 16 + l15) * 64 + ks * 32 + l4 * 8];
  }
  f32x4 acc[2][4];
#pragma unroll
  for (int i = 0; i < 2; ++i)
#pragma unroll
    for (int j = 0; j < 4; ++j) acc[i][j] = {0.f, 0.f, 0.f, 0.f};
#pragma unroll
  for (int ks = 0; ks < 2; ++ks)
#pragma unroll
    for (int i = 0; i < 2; ++i)
#pragma unroll
      for (int j = 0; j < 4; ++j)
        acc[i][j] = __builtin_amdgcn_mfma_f32_16x16x32_bf16(av[i][ks], bv[j][ks],
                                                            acc[i][j], 0, 0, 0);

  __syncthreads();
  float dpart[2] = {0.f, 0.f};
#pragma unroll
  for (int ks = 0; ks < 2; ++ks)
#pragma unroll
    for (int i = 0; i < 2; ++i)
#pragma unroll
      for (int t = 0; t < 8; ++t)
        dpart[i] += bf2f((unsigned short)av[i][ks][t]) * kss[ks * 32 + l4 * 8 + t];
#pragma unroll
  for (int i = 0; i < 2; ++i) {
    dpart[i] += __shfl_xor(dpart[i], 16);
    dpart[i] += __shfl_xor(dpart[i], 32);
    if (l4 == 0) {
      dnls[wv * 32 + i * 16 + l15] = dpart[i];
      denom[(size_t)bh * Nn + rowb + i * 16 + l15] = dpart[i];
    }
  }
  __syncthreads();
#pragma unroll
  for (int i = 0; i < 2; ++i) {
#pragma unroll
    for (int r = 0; r < 4; ++r) {
      const int rl = i * 16 + l4 * 4 + r;
      const float rd = 1.0f / dnls[wv * 32 + rl];
      const int nrow = rowb + rl;
#pragma unroll
      for (int j = 0; j < 4; ++j)
        oph[((size_t)b * Nn + nrow) * Cc + h * 64 + j * 16 + l15] =
            f2bf(acc[i][j][r] * rd);
    }
  }
}

extern "C" void kernel_launch(void* const* d_in, const int* in_sizes, int n_in,
                              void* d_out, int out_size, void* d_ws, size_t ws_size,
                              hipStream_t stream) {
  const float* x = (const float*)d_in[0];
  const float* w_qkv = (const float*)d_in[1];
  const float* w_proj = (const float*)d_in[2];
  const float* b_proj = (const float*)d_in[3];
  float* out = (float*)d_out;
  float* attn = out + (size_t)Bb * Nn * Cc;

  float* ws = (float*)d_ws;
  float* kvpart = ws;                        // 1572864
  float* kspart = kvpart + 1572864;          // 24576
  float* ksum = kspart + 24576;              // 2048 (padded)
  float* denom = ksum + 2048;                // 49152
  unsigned short* us = (unsigned short*)(denom + 49152);
  unsigned short* xh = us;                   // 3145728
  unsigned short* wqh = xh + 3145728;        // 1769472
  unsigned short* qpb = wqh + 1769472;       // 3145728
  unsigned short* kpb = qpb + 3145728;       // 3145728
  unsigned short* vpb = kpb + 3145728;       // 3145728
  unsigned short* kvtb = vpb + 3145728;      // 98304
  unsigned short* oph = kvtb + 98304;        // 3145728
  unsigned short* wph = oph + 3145728;       // 589824

  // 1. input casts
  fused_cast<<<dim3(XBLK + WQBLK + WPBLK), BDIM, 0, stream>>>(x, w_qkv, w_proj, xh, wqh,
                                                              wph);
  // 2. qkv GEMM (XCD-swizzled), fused elu+1 + [B,H,N,D] bf16 epilogue
  gemm_qkv_k<<<dim3(576), BDIM, 0, stream>>>(xh, wqh, qpb, kpb, vpb);
  // 3-4. KV = k'^T v, reduce -> KV^T bf16 + ksum
  kv_partial<<<dim3(NCHUNK, BH), BDIM, 0, stream>>>(kpb, vpb, kvpart, kspart);
  kv_reduce<<<dim3(16, BH), BDIM, 0, stream>>>(kvpart, kspart, kvtb, ksum);
  // 5. denom + out_pre via register MFMA
  outpre_mfma<<<dim3(Nn / 128, BH), BDIM, 0, stream>>>(qpb, kvtb, ksum, denom, oph);
  // 6. attn (swizzled, nt stores) UNION proj (overlapped in one launch)
  attn_proj_k<<<dim3(6144 + 192), BDIM, 0, stream>>>(qpb, kpb, denom, attn,
                                                     oph, wph, b_proj, out);
}